// Round 7
// baseline (350.737 us; speedup 1.0000x reference)
//
#include <hip/hip_runtime.h>
#include <hip/hip_bf16.h>

// Joiner: logits[n,t,u,v] = sum_d tanh(enc[n,t,d]+dec[n,u,d]) * W[v,d] + b[v]
// N=8 T=200 U=100 D=512 V=500  -> GEMM M=160000, K=512, N=500 (padded 512)
//
// R6: TWO-KERNEL SPLIT (R0-R5 showed the fused barrier-per-K-step structure
// serializes phases: no pipe ever >25% busy, dur ~= sum of parts).
//  K1 tanh_act: streaming tanh -> bf16 act[160000][512] in d_ws (~164 MB).
//  K2 gemm_split: barrier-free K-loop GEMM; A direct global->VGPR (L1/L3),
//     B direct from L2-resident pre-tiled Wt, acc[4][4]=64 regs -> 4 waves/
//     SIMD; streamed LDS epilogue. Fallback to R2 fused kernel if ws small.

#define NB 8
#define TT 200
#define UU 100
#define DD 512
#define VV 500
#define VP 512
#define MROWS (NB*TT*UU)   // 160000

typedef __attribute__((ext_vector_type(4))) float  f32x4;
typedef __attribute__((ext_vector_type(8))) short  s16x8;

__device__ __forceinline__ unsigned short f2bf(float f) {
    unsigned int u = __builtin_bit_cast(unsigned int, f);
    u = (u + 0x7FFFu + ((u >> 16) & 1u)) >> 16;   // round-to-nearest-even
    return (unsigned short)u;
}

__device__ __forceinline__ float fast_tanh(float x) {
    float e = __expf(2.0f * x);
    return 1.0f - 2.0f * __builtin_amdgcn_rcpf(e + 1.0f);
}

// ---- prep: W (500x512 f32) -> bf16, padded to 512 rows, tiled [kc][v][32] ----
__global__ void prep_w(const float* __restrict__ W, unsigned short* __restrict__ Wt) {
    int idx = blockIdx.x * 256 + threadIdx.x;   // 0 .. 512*512-1
    int k = idx & 511;
    int v = idx >> 9;
    float val = (v < VV) ? W[v * DD + k] : 0.0f;
    Wt[(k >> 5) * (VP * 32) + v * 32 + (k & 31)] = f2bf(val);
}

// =================== PATH A: two-kernel split ===================

// ---- K1: act[row][k] = bf16(tanh(enc+dec)), 8 elems/thread/iter ----
#define T1GRID 4096
__global__ __launch_bounds__(256) void tanh_act(
    const float* __restrict__ enc, const float* __restrict__ dec,
    unsigned short* __restrict__ act)
{
    const int total = MROWS * (DD / 8);          // 10,240,000 units
    for (int idx = blockIdx.x * 256 + threadIdx.x; idx < total;
         idx += T1GRID * 256) {
        int row = idx >> 6;
        int k8  = (idx & 63) << 3;
        int n   = row / (TT * UU);
        int rem = row - n * (TT * UU);
        int t   = rem / UU;
        int u   = rem - t * UU;
        const float* ep = enc + (n * TT + t) * DD + k8;
        const float* dp = dec + (n * UU + u) * DD + k8;
        f32x4 e0 = *(const f32x4*)(ep);
        f32x4 e1 = *(const f32x4*)(ep + 4);
        f32x4 d0 = *(const f32x4*)(dp);
        f32x4 d1 = *(const f32x4*)(dp + 4);
        s16x8 av;
        #pragma unroll
        for (int j = 0; j < 4; ++j) av[j]     = (short)f2bf(fast_tanh(e0[j] + d0[j]));
        #pragma unroll
        for (int j = 0; j < 4; ++j) av[4 + j] = (short)f2bf(fast_tanh(e1[j] + d1[j]));
        *(s16x8*)(act + (long)row * DD + k8) = av;
    }
}

// ---- K2: GEMM act @ Wt^T + b. BM=128, BN=256 (vb=blockIdx.y), 512 thr,
//      8 waves (2 wm x 4 wn), wave tile 64x64, acc[4][4]. NO K-loop barriers.
#define GLCH 264
__global__ __launch_bounds__(512, 4) void gemm_split(
    const unsigned short* __restrict__ act, const unsigned short* __restrict__ Wt,
    const float* __restrict__ bias, float* __restrict__ out)
{
    __shared__ __align__(16) float lchunk[32 * GLCH];   // 33792 B

    const int tid  = threadIdx.x;
    const int mb   = blockIdx.x;
    const int vb   = blockIdx.y;     // 0,1: 256-col slab
    const int lane = tid & 63;
    const int w    = tid >> 6;
    const int wm   = w >> 2;         // 0..1: 64-row half
    const int wn   = w & 3;          // 0..3: 64-col quarter
    const int lr   = lane & 15;
    const int lk   = lane >> 4;

    f32x4 acc[4][4];
    #pragma unroll
    for (int m = 0; m < 4; ++m)
        #pragma unroll
        for (int f = 0; f < 4; ++f)
            acc[m][f] = (f32x4){0.f, 0.f, 0.f, 0.f};

    // A: act[(mb*128 + wm*64 + m*16 + lr)][kc*32 + lk*8]
    const unsigned short* aptr = act + (long)(mb * 128 + wm * 64 + lr) * DD + lk * 8;
    // B: Wt[kc][vb*256 + wn*64 + f*16 + lr][lk*8]
    const unsigned short* wptr = Wt + (vb * 256 + wn * 64 + lr) * 32 + lk * 8;

    for (int kc = 0; kc < 16; ++kc) {
        s16x8 aF[4], bF[4];
        #pragma unroll
        for (int f = 0; f < 4; ++f)
            bF[f] = *(const s16x8*)(wptr + kc * (VP * 32) + f * (16 * 32));
        #pragma unroll
        for (int m = 0; m < 4; ++m)
            aF[m] = *(const s16x8*)(aptr + (long)(m * 16) * DD + kc * 32);

        __builtin_amdgcn_s_setprio(1);
        #pragma unroll
        for (int m = 0; m < 4; ++m)
            #pragma unroll
            for (int f = 0; f < 4; ++f)
                acc[m][f] = __builtin_amdgcn_mfma_f32_16x16x32_bf16(aF[m], bF[f], acc[m][f], 0, 0, 0);
        __builtin_amdgcn_s_setprio(0);
    }

    // ---- epilogue: streamed via LDS 32-row chunks ----
    float bv[4];
    #pragma unroll
    for (int f = 0; f < 4; ++f) {
        int v = vb * 256 + wn * 64 + f * 16 + lr;
        bv[f] = (v < VV) ? bias[v] : 0.0f;
    }
    const int slabcols = (vb == 0) ? 256 : (VV - 256);   // 256 or 244
    const int segmax   = slabcols >> 2;                  // 64 or 61
    float* outbase = out + (long)mb * 128 * VV + vb * 256;

    for (int c = 0; c < 4; ++c) {
        if (c) __syncthreads();
        if (wm == (c >> 1)) {
            #pragma unroll
            for (int mm = 0; mm < 2; ++mm) {
                int m = (c & 1) * 2 + mm;
                #pragma unroll
                for (int f = 0; f < 4; ++f) {
                    int vloc = wn * 64 + f * 16 + lr;
                    #pragma unroll
                    for (int q = 0; q < 4; ++q)
                        lchunk[(mm * 16 + lk * 4 + q) * GLCH + vloc] = acc[m][f][q] + bv[f];
                }
            }
        }
        __syncthreads();
        float* dst = outbase + (long)c * 32 * VV;
        #pragma unroll
        for (int i = 0; i < 4; ++i) {
            int idx2 = i * 512 + tid;      // 0..2047
            int rw = idx2 >> 6;
            int sg = idx2 & 63;
            if (sg < segmax)
                *(f32x4*)(dst + (long)rw * VV + sg * 4) =
                    *(const f32x4*)(lchunk + rw * GLCH + sg * 4);
        }
    }
}

// =================== PATH B: R2 fused fallback (144.6 us) ===================
#define FBM 64
#define FLDA 40
__global__ __launch_bounds__(256, 2) void joiner_fused(
    const float* __restrict__ enc, const float* __restrict__ dec,
    const unsigned short* __restrict__ Wt, const float* __restrict__ bias,
    float* __restrict__ out)
{
    __shared__ __align__(16) char smem[32000];
    unsigned short* lA0 = (unsigned short*)smem;
    unsigned short* lA1 = (unsigned short*)(smem + FBM * FLDA * 2);

    const int tid  = threadIdx.x;
    const int mb   = blockIdx.x;
    const int lane = tid & 63;
    const int wn   = tid >> 6;
    const int lr   = lane & 15;
    const int lk   = lane >> 4;
    const int srow = tid >> 2;
    const int sk   = (tid & 3) << 3;

    int r   = mb * FBM + srow;
    int n   = r / (TT * UU);
    int rem = r - n * (TT * UU);
    int t   = rem / UU;
    int u   = rem - t * UU;
    const float* ep = enc + (n * TT + t) * DD + sk;
    const float* dp = dec + (n * UU + u) * DD + sk;

    f32x4 e0, e1, d0, d1;
    e0 = *(const f32x4*)(ep);     e1 = *(const f32x4*)(ep + 4);
    d0 = *(const f32x4*)(dp);     d1 = *(const f32x4*)(dp + 4);
    {
        s16x8 av;
        #pragma unroll
        for (int j = 0; j < 4; ++j) av[j]     = (short)f2bf(fast_tanh(e0[j] + d0[j]));
        #pragma unroll
        for (int j = 0; j < 4; ++j) av[4 + j] = (short)f2bf(fast_tanh(e1[j] + d1[j]));
        *(s16x8*)(&lA0[srow * FLDA + sk]) = av;
    }
    e0 = *(const f32x4*)(ep + 32);     e1 = *(const f32x4*)(ep + 36);
    d0 = *(const f32x4*)(dp + 32);     d1 = *(const f32x4*)(dp + 36);
    __syncthreads();

    f32x4 acc[4][8];
    #pragma unroll
    for (int m = 0; m < 4; ++m)
        #pragma unroll
        for (int f = 0; f < 8; ++f)
            acc[m][f] = (f32x4){0.f, 0.f, 0.f, 0.f};

    const unsigned short* wptr = Wt + (wn * 128 + lr) * 32 + lk * 8;

    for (int kc = 0; kc < 16; ++kc) {
        unsigned short* lCur = (kc & 1) ? lA1 : lA0;
        unsigned short* lNxt = (kc & 1) ? lA0 : lA1;

        s16x8 bF[8];
        #pragma unroll
        for (int f = 0; f < 8; ++f)
            bF[f] = *(const s16x8*)(wptr + kc * (VP * 32) + f * (16 * 32));

        s16x8 aF[4];
        #pragma unroll
        for (int m = 0; m < 4; ++m)
            aF[m] = *(const s16x8*)(&lCur[(m * 16 + lr) * FLDA + lk * 8]);

        if (kc < 15) {
            s16x8 av;
            #pragma unroll
            for (int j = 0; j < 4; ++j) av[j]     = (short)f2bf(fast_tanh(e0[j] + d0[j]));
            #pragma unroll
            for (int j = 0; j < 4; ++j) av[4 + j] = (short)f2bf(fast_tanh(e1[j] + d1[j]));
            *(s16x8*)(&lNxt[srow * FLDA + sk]) = av;
            if (kc < 14) {
                const float* ep2 = ep + (kc + 2) * 32;
                const float* dp2 = dp + (kc + 2) * 32;
                e0 = *(const f32x4*)(ep2);     e1 = *(const f32x4*)(ep2 + 4);
                d0 = *(const f32x4*)(dp2);     d1 = *(const f32x4*)(dp2 + 4);
            }
        }

        __builtin_amdgcn_s_setprio(1);
        #pragma unroll
        for (int m = 0; m < 4; ++m)
            #pragma unroll
            for (int f = 0; f < 8; ++f)
                acc[m][f] = __builtin_amdgcn_mfma_f32_16x16x32_bf16(aF[m], bF[f], acc[m][f], 0, 0, 0);
        __builtin_amdgcn_s_setprio(0);

        __syncthreads();
    }

    float bv[8];
    #pragma unroll
    for (int f = 0; f < 8; ++f) {
        int v = wn * 128 + f * 16 + lr;
        bv[f] = (v < VV) ? bias[v] : 0.0f;
    }

    float* lchunk = (float*)smem;
    float* outbase = out + (long)mb * FBM * VV;

    for (int m = 0; m < 4; ++m) {
        __syncthreads();
        #pragma unroll
        for (int f = 0; f < 8; ++f) {
            int v = wn * 128 + f * 16 + lr;
            if (v < VV) {
                #pragma unroll
                for (int q = 0; q < 4; ++q)
                    lchunk[(lk * 4 + q) * VV + v] = acc[m][f][q] + bv[f];
            }
        }
        __syncthreads();
        float* dst = outbase + m * 16 * VV;
        #pragma unroll
        for (int i = 0; i < 8; ++i) {
            int c = i * 256 + tid;
            if (c < 2000)
                *(f32x4*)(dst + c * 4) = *(const f32x4*)(lchunk + c * 4);
        }
    }
}

extern "C" void kernel_launch(void* const* d_in, const int* in_sizes, int n_in,
                              void* d_out, int out_size, void* d_ws, size_t ws_size,
                              hipStream_t stream) {
    const float* enc = (const float*)d_in[0];
    const float* dec = (const float*)d_in[1];
    const float* W   = (const float*)d_in[2];
    const float* b   = (const float*)d_in[3];
    float* out = (float*)d_out;

    const size_t actBytes = (size_t)MROWS * DD * 2;          // 163,840,000
    const size_t wtBytes  = (size_t)VP * DD * 2;             // 524,288

    if (ws_size >= actBytes + wtBytes) {
        unsigned short* act = (unsigned short*)d_ws;
        unsigned short* Wt  = (unsigned short*)((char*)d_ws + actBytes);
        prep_w<<<dim3((VP * DD) / 256), dim3(256), 0, stream>>>(W, Wt);
        tanh_act<<<dim3(T1GRID), dim3(256), 0, stream>>>(enc, dec, act);
        gemm_split<<<dim3(MROWS / 128, 2), dim3(512), 0, stream>>>(act, Wt, b, out);
    } else {
        unsigned short* Wt = (unsigned short*)d_ws;
        prep_w<<<dim3((VP * DD) / 256), dim3(256), 0, stream>>>(W, Wt);
        joiner_fused<<<dim3(MROWS / FBM), dim3(256), 0, stream>>>(enc, dec, Wt, b, out);
    }
}

// Round 8
// 278.024 us; speedup vs baseline: 1.2615x; 1.2615x over previous
//
#include <hip/hip_runtime.h>
#include <hip/hip_bf16.h>

// Joiner: logits[n,t,u,v] = sum_d tanh(enc[n,t,d]+dec[n,u,d]) * W[v,d] + b[v]
// N=8 T=200 U=100 D=512 V=500  -> GEMM M=160000, K=512, N=500 (padded 512)
//
// R7: FUSED + BARRIER-FREE K-LOOP. A-fragments are computed tanh->bf16
// DIRECTLY in registers: mfma_16x16x32 A layout (row=lane&15, k=(lane>>4)*8)
// means each lane's 8-elem fragment slice is a private (row,k8) tanh job --
// no LDS, no barriers, no cross-lane traffic in the K-loop. The 4 waves of a
// block redundantly compute the same 64 rows (4x tanh, ~530 VALU cyc/step vs
// 620 matrix cyc/step per SIMD) but VALU overlaps the matrix pipe across
// free-running waves (R0-R5 showed barrier-locked phases serialize: no pipe
// ever >25% busy). B direct global->VGPR from L2-resident pre-tiled Wt.
// Epilogue: R2's streaming LDS full-row chunks (ideal 320 MB writes).

#define NB 8
#define TT 200
#define UU 100
#define DD 512
#define VV 500
#define VP 512
#define BM 64
#define BK 32
#define KSTEPS 16          // 512/32
#define THREADS 256
#define MROWS (NB*TT*UU)   // 160000
#define MBLOCKS (MROWS/BM) // 2500

typedef __attribute__((ext_vector_type(4))) float         f32x4;
typedef __attribute__((ext_vector_type(8))) short         s16x8;
typedef __attribute__((ext_vector_type(4))) unsigned int  u32x4;

__device__ __forceinline__ unsigned short f2bf(float f) {
    unsigned int u = __builtin_bit_cast(unsigned int, f);
    u = (u + 0x7FFFu + ((u >> 16) & 1u)) >> 16;   // round-to-nearest-even
    return (unsigned short)u;
}

// pack 2 f32 -> 2 bf16 in one instruction (RNE), dst = [hi:bf16(b)|lo:bf16(a)]
__device__ __forceinline__ unsigned int cvt_pk_bf16(float a, float b) {
    unsigned int r;
    asm("v_cvt_pk_bf16_f32 %0, %1, %2" : "=v"(r) : "v"(a), "v"(b));
    return r;
}

__device__ __forceinline__ float fast_tanh(float x) {
    // tanh(x) = 1 - 2/(1+2^(x*2*log2e)); saturations via exp inf/0
    float e = __builtin_amdgcn_exp2f(x * 2.88539008177793f);
    return __builtin_fmaf(-2.0f, __builtin_amdgcn_rcpf(e + 1.0f), 1.0f);
}

// ---- prep: W (500x512 f32) -> bf16, padded to 512 rows, tiled [kc][v][32] ----
__global__ void prep_w(const float* __restrict__ W, unsigned short* __restrict__ Wt) {
    int idx = blockIdx.x * 256 + threadIdx.x;   // 0 .. 512*512-1
    int k = idx & 511;
    int v = idx >> 9;
    float val = (v < VV) ? W[v * DD + k] : 0.0f;
    Wt[(k >> 5) * (VP * BK) + v * BK + (k & 31)] = f2bf(val);
}

__global__ __launch_bounds__(THREADS, 2) void joiner_kernel(
    const float* __restrict__ enc, const float* __restrict__ dec,
    const unsigned short* __restrict__ Wt, const float* __restrict__ bias,
    float* __restrict__ out)
{
    __shared__ __align__(16) float lchunk[16 * VV];   // 32000 B (epilogue only)

    const int tid  = threadIdx.x;
    const int mb   = blockIdx.x;
    const int lane = tid & 63;
    const int wn   = tid >> 6;       // 0..3: 128-col quarter
    const int lr   = lane & 15;      // fragment row / C col
    const int lk   = lane >> 4;      // k-slice selector

    // per-lane enc/dec pointers for the 4 m-fragments (row = mb*64+m*16+lr)
    const float* ep[4];
    const float* dp[4];
    #pragma unroll
    for (int m = 0; m < 4; ++m) {
        int r   = mb * BM + m * 16 + lr;
        int n   = r / (TT * UU);
        int rem = r - n * (TT * UU);
        int t   = rem / UU;
        int u   = rem - t * UU;
        ep[m] = enc + (n * TT + t) * DD + lk * 8;
        dp[m] = dec + (n * UU + u) * DD + lk * 8;
    }

    f32x4 acc[4][8];
    #pragma unroll
    for (int m = 0; m < 4; ++m)
        #pragma unroll
        for (int f = 0; f < 8; ++f)
            acc[m][f] = (f32x4){0.f, 0.f, 0.f, 0.f};

    // per-thread B pointer into pre-tiled Wt: v = wn*128 + f*16 + lr, k = lk*8
    const unsigned short* wptr = Wt + (wn * 128 + lr) * BK + lk * 8;

    for (int kc = 0; kc < KSTEPS; ++kc) {
        // ---- B fragments: direct global->VGPR (L2/L1-hit, 1KB/wave/frag) ----
        s16x8 bF[8];
        #pragma unroll
        for (int f = 0; f < 8; ++f)
            bF[f] = *(const s16x8*)(wptr + kc * (VP * BK) + f * (16 * BK));

        // ---- A fragments: load enc/dec slices, tanh, pack -- in registers ----
        s16x8 aF[4];
        #pragma unroll
        for (int m = 0; m < 4; ++m) {
            const float* e = ep[m] + kc * BK;
            const float* d = dp[m] + kc * BK;
            f32x4 e0 = *(const f32x4*)(e);
            f32x4 e1 = *(const f32x4*)(e + 4);
            f32x4 d0 = *(const f32x4*)(d);
            f32x4 d1 = *(const f32x4*)(d + 4);
            float t0 = fast_tanh(e0[0] + d0[0]);
            float t1 = fast_tanh(e0[1] + d0[1]);
            float t2 = fast_tanh(e0[2] + d0[2]);
            float t3 = fast_tanh(e0[3] + d0[3]);
            float t4 = fast_tanh(e1[0] + d1[0]);
            float t5 = fast_tanh(e1[1] + d1[1]);
            float t6 = fast_tanh(e1[2] + d1[2]);
            float t7 = fast_tanh(e1[3] + d1[3]);
            u32x4 wds;
            wds[0] = cvt_pk_bf16(t0, t1);
            wds[1] = cvt_pk_bf16(t2, t3);
            wds[2] = cvt_pk_bf16(t4, t5);
            wds[3] = cvt_pk_bf16(t6, t7);
            aF[m] = __builtin_bit_cast(s16x8, wds);
        }

        // ---- 32 MFMAs ----
        __builtin_amdgcn_s_setprio(1);
        #pragma unroll
        for (int m = 0; m < 4; ++m)
            #pragma unroll
            for (int f = 0; f < 8; ++f)
                acc[m][f] = __builtin_amdgcn_mfma_f32_16x16x32_bf16(aF[m], bF[f], acc[m][f], 0, 0, 0);
        __builtin_amdgcn_s_setprio(0);
    }

    // ---- epilogue: acc -> LDS 16-row chunks -> streaming f32x4 stores ----
    float bv[8];
    #pragma unroll
    for (int f = 0; f < 8; ++f) {
        int v = wn * 128 + f * 16 + lr;
        bv[f] = (v < VV) ? bias[v] : 0.0f;
    }

    float* outbase = out + (long)mb * BM * VV;

    for (int m = 0; m < 4; ++m) {
        __syncthreads();   // waves converge / previous chunk fully streamed
        #pragma unroll
        for (int f = 0; f < 8; ++f) {
            int v = wn * 128 + f * 16 + lr;
            if (v < VV) {
                #pragma unroll
                for (int q = 0; q < 4; ++q)
                    lchunk[(lk * 4 + q) * VV + v] = acc[m][f][q] + bv[f];
            }
        }
        __syncthreads();
        // 16 rows x 500 f32 = 8000 contiguous floats = 2000 f32x4
        float* dst = outbase + m * 16 * VV;
        #pragma unroll
        for (int i = 0; i < 8; ++i) {
            int c = i * THREADS + tid;
            if (c < 2000)
                *(f32x4*)(dst + c * 4) = *(const f32x4*)(lchunk + c * 4);
        }
    }
}

extern "C" void kernel_launch(void* const* d_in, const int* in_sizes, int n_in,
                              void* d_out, int out_size, void* d_ws, size_t ws_size,
                              hipStream_t stream) {
    const float* enc = (const float*)d_in[0];
    const float* dec = (const float*)d_in[1];
    const float* W   = (const float*)d_in[2];
    const float* b   = (const float*)d_in[3];
    float* out = (float*)d_out;
    unsigned short* Wt = (unsigned short*)d_ws;   // 512*512*2 = 512 KB

    prep_w<<<dim3((VP * DD) / 256), dim3(256), 0, stream>>>(W, Wt);
    joiner_kernel<<<dim3(MBLOCKS), dim3(THREADS), 0, stream>>>(enc, dec, Wt, b, out);
}

// Round 10
// 181.662 us; speedup vs baseline: 1.9307x; 1.5304x over previous
//
#include <hip/hip_runtime.h>
#include <hip/hip_bf16.h>

// Joiner: logits[n,t,u,v] = sum_d tanh(enc[n,t,d]+dec[n,u,d]) * W[v,d] + b[v]
// N=8 T=200 U=100 D=512 V=500  -> GEMM M=160000, K=512, N=500 (padded 512)
//
// R8 (resubmit after infra failure): STAGE-ONCE + BARRIER-FREE K-LOOP.
// Prologue stages the whole 64x512 A-tile (tanh once, coalesced 128B/lane
// loads, cvt_pk pack) into a 64KB XOR-swizzled LDS tile; ONE barrier; then
// 16 K-steps with no barriers -- waves free-run so MFMA / B-L2-loads / VALU
// / writes overlap across the 8 resident waves per CU (R0-R5: barrier-locked
// phases serialize, no pipe >25% busy; R7: tanh redundancy + scattered loads
// kill the trans pipe). Row stride 1024B (mult of 128B) + slot^(row&7)
// swizzle = uniform banks. Epilogue: streamed LDS chunks (ideal WRITE_SIZE).

#define NB 8
#define TT 200
#define UU 100
#define DD 512
#define VV 500
#define VP 512
#define BM 64
#define BK 32
#define KSTEPS 16          // 512/32
#define THREADS 256
#define MROWS (NB*TT*UU)   // 160000
#define MBLOCKS (MROWS/BM) // 2500

typedef __attribute__((ext_vector_type(4))) float         f32x4;
typedef __attribute__((ext_vector_type(8))) short         s16x8;
typedef __attribute__((ext_vector_type(4))) unsigned int  u32x4;

__device__ __forceinline__ unsigned short f2bf(float f) {
    unsigned int u = __builtin_bit_cast(unsigned int, f);
    u = (u + 0x7FFFu + ((u >> 16) & 1u)) >> 16;   // round-to-nearest-even
    return (unsigned short)u;
}

// pack 2 f32 -> 2 bf16 (RNE) in one instruction
__device__ __forceinline__ unsigned int cvt_pk_bf16(float a, float b) {
    unsigned int r;
    asm("v_cvt_pk_bf16_f32 %0, %1, %2" : "=v"(r) : "v"(a), "v"(b));
    return r;
}

__device__ __forceinline__ float fast_tanh(float x) {
    // tanh(x) = 1 - 2/(1+2^(2x*log2e)); saturations via exp inf/0
    float e = __builtin_amdgcn_exp2f(x * 2.88539008177793f);
    return __builtin_fmaf(-2.0f, __builtin_amdgcn_rcpf(e + 1.0f), 1.0f);
}

// ---- prep: W (500x512 f32) -> bf16, padded to 512 rows, tiled [kc][v][32] ----
__global__ void prep_w(const float* __restrict__ W, unsigned short* __restrict__ Wt) {
    int idx = blockIdx.x * 256 + threadIdx.x;   // 0 .. 512*512-1
    int k = idx & 511;
    int v = idx >> 9;
    float val = (v < VV) ? W[v * DD + k] : 0.0f;
    Wt[(k >> 5) * (VP * BK) + v * BK + (k & 31)] = f2bf(val);
}

__global__ __launch_bounds__(THREADS, 2) void joiner_kernel(
    const float* __restrict__ enc, const float* __restrict__ dec,
    const unsigned short* __restrict__ Wt, const float* __restrict__ bias,
    float* __restrict__ out)
{
    // 64 rows x 512 shorts (1024B stride) = 64KB; unioned with epilogue chunk
    __shared__ __align__(16) char smem[65536];
    unsigned short* lA = (unsigned short*)smem;
    float* lchunk = (float*)smem;               // 16*500 f32 = 32000 B

    const int tid  = threadIdx.x;
    const int mb   = blockIdx.x;
    const int lane = tid & 63;
    const int wn   = tid >> 6;       // 0..3: 128-col quarter
    const int lr   = lane & 15;      // fragment row / C col
    const int lk   = lane >> 4;      // k-slice selector

    // staging geometry: thread owns row srow, k-quarter kq (128 wide)
    const int srow = tid >> 2;          // 0..63
    const int kq   = (tid & 3) << 7;    // 0,128,256,384

    int r   = mb * BM + srow;
    int n   = r / (TT * UU);
    int rem = r - n * (TT * UU);
    int t   = rem / UU;
    int u   = rem - t * UU;
    const float* ep = enc + (n * TT + t) * DD + kq;
    const float* dp = dec + (n * UU + u) * DD + kq;

    // ---- prologue: stage 64x512 tanh-activations, 4 passes x 32 elems ----
    #pragma unroll 2
    for (int cp = 0; cp < 4; ++cp) {
        const float* e = ep + cp * 32;
        const float* d = dp + cp * 32;
        f32x4 ev[8], dv[8];
        #pragma unroll
        for (int i = 0; i < 8; ++i) ev[i] = *(const f32x4*)(e + i * 4);
        #pragma unroll
        for (int i = 0; i < 8; ++i) dv[i] = *(const f32x4*)(d + i * 4);
        #pragma unroll
        for (int j = 0; j < 4; ++j) {
            u32x4 wds;
            #pragma unroll
            for (int h = 0; h < 2; ++h) {
                int i = j * 2 + h;
                float t0 = fast_tanh(ev[i][0] + dv[i][0]);
                float t1 = fast_tanh(ev[i][1] + dv[i][1]);
                float t2 = fast_tanh(ev[i][2] + dv[i][2]);
                float t3 = fast_tanh(ev[i][3] + dv[i][3]);
                wds[h * 2 + 0] = cvt_pk_bf16(t0, t1);
                wds[h * 2 + 1] = cvt_pk_bf16(t2, t3);
            }
            int slot = (tid & 3) * 16 + cp * 4 + j;   // 16B slot (8 bf16)
            int swz  = slot ^ (srow & 7);
            *(u32x4*)(&lA[srow * 512 + swz * 8]) = wds;
        }
    }
    __syncthreads();   // the ONLY barrier before the epilogue

    f32x4 acc[4][8];
    #pragma unroll
    for (int m = 0; m < 4; ++m)
        #pragma unroll
        for (int f = 0; f < 8; ++f)
            acc[m][f] = (f32x4){0.f, 0.f, 0.f, 0.f};

    // per-thread B pointer into pre-tiled Wt: v = wn*128 + f*16 + lr, k = lk*8
    const unsigned short* wptr = Wt + (wn * 128 + lr) * BK + lk * 8;

    // ---- K-loop: barrier-free ----
    for (int kc = 0; kc < KSTEPS; ++kc) {
        // A fragments (swizzled ds_read_b128, uniform bank spread)
        s16x8 aF[4];
        #pragma unroll
        for (int m = 0; m < 4; ++m) {
            int row = m * 16 + lr;
            int swz = (kc * 4 + lk) ^ (lr & 7);
            aF[m] = *(const s16x8*)(&lA[row * 512 + swz * 8]);
        }
        // B fragments in two halves of 4 (limits live regs to ~16)
        s16x8 bF[4];
        #pragma unroll
        for (int f = 0; f < 4; ++f)
            bF[f] = *(const s16x8*)(wptr + kc * (VP * BK) + f * (16 * BK));
        __builtin_amdgcn_s_setprio(1);
        #pragma unroll
        for (int m = 0; m < 4; ++m)
            #pragma unroll
            for (int f = 0; f < 4; ++f)
                acc[m][f] = __builtin_amdgcn_mfma_f32_16x16x32_bf16(aF[m], bF[f], acc[m][f], 0, 0, 0);
        __builtin_amdgcn_s_setprio(0);
        #pragma unroll
        for (int f = 0; f < 4; ++f)
            bF[f] = *(const s16x8*)(wptr + kc * (VP * BK) + (f + 4) * (16 * BK));
        __builtin_amdgcn_s_setprio(1);
        #pragma unroll
        for (int m = 0; m < 4; ++m)
            #pragma unroll
            for (int f = 0; f < 4; ++f)
                acc[m][f + 4] = __builtin_amdgcn_mfma_f32_16x16x32_bf16(aF[m], bF[f], acc[m][f + 4], 0, 0, 0);
        __builtin_amdgcn_s_setprio(0);
    }

    // ---- epilogue: acc -> LDS 16-row chunks -> streaming f32x4 stores ----
    float bv[8];
    #pragma unroll
    for (int f = 0; f < 8; ++f) {
        int v = wn * 128 + f * 16 + lr;
        bv[f] = (v < VV) ? bias[v] : 0.0f;
    }

    float* outbase = out + (long)mb * BM * VV;

    for (int m = 0; m < 4; ++m) {
        __syncthreads();   // waves converge / previous chunk fully streamed
        #pragma unroll
        for (int f = 0; f < 8; ++f) {
            int v = wn * 128 + f * 16 + lr;
            if (v < VV) {
                #pragma unroll
                for (int q = 0; q < 4; ++q)
                    lchunk[(lk * 4 + q) * VV + v] = acc[m][f][q] + bv[f];
            }
        }
        __syncthreads();
        // 16 rows x 500 f32 = 8000 contiguous floats = 2000 f32x4
        float* dst = outbase + m * 16 * VV;
        #pragma unroll
        for (int i = 0; i < 8; ++i) {
            int c = i * THREADS + tid;
            if (c < 2000)
                *(f32x4*)(dst + c * 4) = *(const f32x4*)(lchunk + c * 4);
        }
    }
}

extern "C" void kernel_launch(void* const* d_in, const int* in_sizes, int n_in,
                              void* d_out, int out_size, void* d_ws, size_t ws_size,
                              hipStream_t stream) {
    const float* enc = (const float*)d_in[0];
    const float* dec = (const float*)d_in[1];
    const float* W   = (const float*)d_in[2];
    const float* b   = (const float*)d_in[3];
    float* out = (float*)d_out;
    unsigned short* Wt = (unsigned short*)d_ws;   // 512*512*2 = 512 KB

    prep_w<<<dim3((VP * DD) / 256), dim3(256), 0, stream>>>(W, Wt);
    joiner_kernel<<<dim3(MBLOCKS), dim3(THREADS), 0, stream>>>(enc, dec, Wt, b, out);
}

// Round 12
// 153.984 us; speedup vs baseline: 2.2778x; 1.1797x over previous
//
#include <hip/hip_runtime.h>
#include <hip/hip_bf16.h>

// Joiner: logits[n,t,u,v] = sum_d tanh(enc[n,t,d]+dec[n,u,d]) * W[v,d] + b[v]
// N=8 T=200 U=100 D=512 V=500  -> GEMM M=160000, K=512, N=500 (padded 512)
//
// R9 (resubmit after infra failure): LATENCY ATTACK. (a) B-fragment REGISTER
// DOUBLE-BUFFER across the K-step barrier: step kc issues kc+1's 4 B loads at
// body top, MFMAs use the buffer loaded last step (counted vmcnt, ~1000cyc
// in-flight window). (b) register diet for 3 blocks/CU: V-split BN=256
// (blockIdx.y), wave tile 64x64, acc[4][4]=64 + bCur16 + bNxt16 + aF16 +
// e/d16 ~= 150 unified regs <= 170 -> 3 waves/SIMD (every prior round sat at
// 2). A-tile tanh-staged in dbuf LDS, stage moved AFTER MFMA (its e/d loads
// issue at body top, hidden under the MFMA block). Streaming LDS epilogue.

#define NB 8
#define TT 200
#define UU 100
#define DD 512
#define VV 500
#define VP 512
#define BM 64
#define BNB 256            // per-block V-columns
#define BK 32
#define KSTEPS 16          // 512/32
#define THREADS 256
#define LDA 40             // BK + 8 pad (ushort units, 80B row stride)
#define LCH 264            // epilogue chunk row stride in f32
#define MROWS (NB*TT*UU)   // 160000
#define MBLOCKS (MROWS/BM) // 2500

typedef __attribute__((ext_vector_type(4))) float         f32x4;
typedef __attribute__((ext_vector_type(8))) short         s16x8;
typedef __attribute__((ext_vector_type(4))) unsigned int  u32x4;

__device__ __forceinline__ unsigned short f2bf(float f) {
    unsigned int u = __builtin_bit_cast(unsigned int, f);
    u = (u + 0x7FFFu + ((u >> 16) & 1u)) >> 16;   // round-to-nearest-even
    return (unsigned short)u;
}

// pack 2 f32 -> 2 bf16 (RNE) in one instruction
__device__ __forceinline__ unsigned int cvt_pk_bf16(float a, float b) {
    unsigned int r;
    asm("v_cvt_pk_bf16_f32 %0, %1, %2" : "=v"(r) : "v"(a), "v"(b));
    return r;
}

__device__ __forceinline__ float fast_tanh(float x) {
    // tanh(x) = 1 - 2/(1+2^(2x*log2e)); saturations via exp inf/0
    float e = __builtin_amdgcn_exp2f(x * 2.88539008177793f);
    return __builtin_fmaf(-2.0f, __builtin_amdgcn_rcpf(e + 1.0f), 1.0f);
}

// ---- prep: W (500x512 f32) -> bf16, padded to 512 rows, tiled [kc][v][32] ----
__global__ void prep_w(const float* __restrict__ W, unsigned short* __restrict__ Wt) {
    int idx = blockIdx.x * 256 + threadIdx.x;   // 0 .. 512*512-1
    int k = idx & 511;
    int v = idx >> 9;
    float val = (v < VV) ? W[v * DD + k] : 0.0f;
    Wt[(k >> 5) * (VP * BK) + v * BK + (k & 31)] = f2bf(val);
}

#define KBODY(kc, CUR, NXT, BC, BNX)                                          \
  {                                                                           \
    if ((kc) < KSTEPS - 1) {                                                  \
      _Pragma("unroll")                                                       \
      for (int f = 0; f < 4; ++f)                                             \
        BNX[f] = *(const s16x8*)(wptr + ((kc)+1) * (VP * BK) + f * (16*BK));  \
      const float* e2 = ep + ((kc)+1) * BK;                                   \
      const float* d2 = dp + ((kc)+1) * BK;                                   \
      e0 = *(const f32x4*)(e2);  e1 = *(const f32x4*)(e2 + 4);                \
      d0 = *(const f32x4*)(d2);  d1 = *(const f32x4*)(d2 + 4);                \
    }                                                                         \
    s16x8 aF[4];                                                              \
    _Pragma("unroll")                                                         \
    for (int m = 0; m < 4; ++m)                                               \
      aF[m] = *(const s16x8*)(&CUR[(m * 16 + lr) * LDA + lk * 8]);            \
    __builtin_amdgcn_s_setprio(1);                                            \
    _Pragma("unroll")                                                         \
    for (int m = 0; m < 4; ++m)                                               \
      _Pragma("unroll")                                                       \
      for (int f = 0; f < 4; ++f)                                             \
        acc[m][f] = __builtin_amdgcn_mfma_f32_16x16x32_bf16(aF[m], BC[f],     \
                                                            acc[m][f],0,0,0); \
    __builtin_amdgcn_s_setprio(0);                                            \
    if ((kc) < KSTEPS - 1) {                                                  \
      u32x4 wds;                                                              \
      wds[0] = cvt_pk_bf16(fast_tanh(e0[0]+d0[0]), fast_tanh(e0[1]+d0[1]));   \
      wds[1] = cvt_pk_bf16(fast_tanh(e0[2]+d0[2]), fast_tanh(e0[3]+d0[3]));   \
      wds[2] = cvt_pk_bf16(fast_tanh(e1[0]+d1[0]), fast_tanh(e1[1]+d1[1]));   \
      wds[3] = cvt_pk_bf16(fast_tanh(e1[2]+d1[2]), fast_tanh(e1[3]+d1[3]));   \
      *(u32x4*)(&NXT[srow * LDA + sk]) = wds;                                 \
    }                                                                         \
    __syncthreads();                                                          \
  }

__global__ __launch_bounds__(THREADS, 3) void joiner_kernel(
    const float* __restrict__ enc, const float* __restrict__ dec,
    const unsigned short* __restrict__ Wt, const float* __restrict__ bias,
    float* __restrict__ out)
{
    // union: K-loop A dbuf (2x5120 B) / epilogue chunk 16 x LCH f32 (16896 B)
    __shared__ __align__(16) char smem[16 * LCH * 4];
    unsigned short* lA0 = (unsigned short*)smem;
    unsigned short* lA1 = (unsigned short*)(smem + BM * LDA * 2);

    const int tid  = threadIdx.x;
    const int mb   = blockIdx.x;
    const int vb   = blockIdx.y;     // 0,1: which 256-col slab of V
    const int lane = tid & 63;
    const int wn   = tid >> 6;       // 0..3: 64-col quarter of the slab
    const int lr   = lane & 15;
    const int lk   = lane >> 4;

    // staging: each thread produces 8 activations of one row
    const int srow = tid >> 2;          // 0..63
    const int sk   = (tid & 3) << 3;    // 0,8,16,24

    int r   = mb * BM + srow;
    int n   = r / (TT * UU);
    int rem = r - n * (TT * UU);
    int t   = rem / UU;
    int u   = rem - t * UU;
    const float* ep = enc + (n * TT + t) * DD + sk;
    const float* dp = dec + (n * UU + u) * DD + sk;

    // per-thread B pointer: v = vb*256 + wn*64 + f*16 + lr, k = lk*8
    const unsigned short* wptr = Wt + (vb * BNB + wn * 64 + lr) * BK + lk * 8;

    f32x4 e0, e1, d0, d1;
    s16x8 b0[4], b1[4];

    // ---- prologue: stage kc=0, issue b0 (kc=0) ----
    e0 = *(const f32x4*)(ep);     e1 = *(const f32x4*)(ep + 4);
    d0 = *(const f32x4*)(dp);     d1 = *(const f32x4*)(dp + 4);
    #pragma unroll
    for (int f = 0; f < 4; ++f)
        b0[f] = *(const s16x8*)(wptr + f * (16 * BK));
    {
        u32x4 wds;
        wds[0] = cvt_pk_bf16(fast_tanh(e0[0]+d0[0]), fast_tanh(e0[1]+d0[1]));
        wds[1] = cvt_pk_bf16(fast_tanh(e0[2]+d0[2]), fast_tanh(e0[3]+d0[3]));
        wds[2] = cvt_pk_bf16(fast_tanh(e1[0]+d1[0]), fast_tanh(e1[1]+d1[1]));
        wds[3] = cvt_pk_bf16(fast_tanh(e1[2]+d1[2]), fast_tanh(e1[3]+d1[3]));
        *(u32x4*)(&lA0[srow * LDA + sk]) = wds;
    }
    __syncthreads();

    f32x4 acc[4][4];
    #pragma unroll
    for (int m = 0; m < 4; ++m)
        #pragma unroll
        for (int f = 0; f < 4; ++f)
            acc[m][f] = (f32x4){0.f, 0.f, 0.f, 0.f};

    // ---- K-loop: 8 x 2 bodies, B reg-dbuf rotates b0/b1, A dbuf lA0/lA1 ----
    #pragma unroll
    for (int kk = 0; kk < KSTEPS; kk += 2) {
        KBODY(kk,     lA0, lA1, b0, b1)
        KBODY(kk + 1, lA1, lA0, b1, b0)
    }

    // ---- epilogue: acc -> LDS 16-row chunks -> streaming f32x4 stores ----
    float bv[4];
    #pragma unroll
    for (int f = 0; f < 4; ++f) {
        int v = vb * BNB + wn * 64 + f * 16 + lr;
        bv[f] = (v < VV) ? bias[v] : 0.0f;
    }

    float* lchunk = (float*)smem;                 // 16 x LCH f32
    const int slabcols = (vb == 0) ? BNB : (VV - BNB);   // 256 or 244
    const int segmax   = slabcols >> 2;                   // 64 or 61
    float* outbase = out + (long)mb * BM * VV + vb * BNB;

    for (int c = 0; c < 4; ++c) {
        __syncthreads();   // LDS free (K-loop done / previous chunk streamed)
        #pragma unroll
        for (int f = 0; f < 4; ++f) {
            int vloc = wn * 64 + f * 16 + lr;
            #pragma unroll
            for (int q = 0; q < 4; ++q)
                lchunk[(lk * 4 + q) * LCH + vloc] = acc[c][f][q] + bv[f];
        }
        __syncthreads();
        // stream 16 rows x slabcols f32; per row a contiguous 1024/976 B run
        float* dst = outbase + c * 16 * VV;
        #pragma unroll
        for (int i = 0; i < 4; ++i) {
            int idx = i * THREADS + tid;        // 0..1023
            int row = idx >> 6;
            int seg = idx & 63;
            if (seg < segmax)
                *(f32x4*)(dst + row * VV + seg * 4) =
                    *(const f32x4*)(lchunk + row * LCH + seg * 4);
        }
    }
}

extern "C" void kernel_launch(void* const* d_in, const int* in_sizes, int n_in,
                              void* d_out, int out_size, void* d_ws, size_t ws_size,
                              hipStream_t stream) {
    const float* enc = (const float*)d_in[0];
    const float* dec = (const float*)d_in[1];
    const float* W   = (const float*)d_in[2];
    const float* b   = (const float*)d_in[3];
    float* out = (float*)d_out;
    unsigned short* Wt = (unsigned short*)d_ws;   // 512*512*2 = 512 KB

    prep_w<<<dim3((VP * DD) / 256), dim3(256), 0, stream>>>(W, Wt);
    joiner_kernel<<<dim3(MBLOCKS, 2), dim3(THREADS), 0, stream>>>(enc, dec, Wt, b, out);
}

// Round 13
// 130.559 us; speedup vs baseline: 2.6864x; 1.1794x over previous
//
#include <hip/hip_runtime.h>
#include <hip/hip_bf16.h>

// Joiner: logits[n,t,u,v] = sum_d tanh(enc[n,t,d]+dec[n,u,d]) * W[v,d] + b[v]
// N=8 T=200 U=100 D=512 V=500  -> GEMM M=160000, K=512, N=500 (padded 512)
//
// R10: R2 (best, 144.6us) + COUNTED-VMCNT CROSS-BARRIER B PREFETCH (T4).
// __syncthreads() drains vmcnt(0) at every K-step barrier, killing any B
// prefetch (R9 lesson). Replace with {s_waitcnt lgkmcnt(0); raw s_barrier}:
// LDS handoff (A dbuf ds_write->ds_read + WAR) stays correct, but the 8
// B-fragment loads issued one step ahead (register dbuf b0/b1) stay IN
// FLIGHT across the barrier; compiler emits counted vmcnt(~12) at consume.
// Everything else identical to R2: BM=64 BN=512 256thr, tanh-staged dbuf
// LDS A (1 barrier/step), streamed LDS epilogue (ideal WRITE_SIZE).

#define NB 8
#define TT 200
#define UU 100
#define DD 512
#define VV 500
#define VP 512
#define BM 64
#define BK 32
#define KSTEPS 16          // 512/32
#define THREADS 256
#define LDA 40             // BK + 8 pad (ushort units, 80B row stride)
#define MROWS (NB*TT*UU)   // 160000
#define MBLOCKS (MROWS/BM) // 2500

typedef __attribute__((ext_vector_type(4))) float         f32x4;
typedef __attribute__((ext_vector_type(8))) short         s16x8;
typedef __attribute__((ext_vector_type(4))) unsigned int  u32x4;

__device__ __forceinline__ unsigned short f2bf(float f) {
    unsigned int u = __builtin_bit_cast(unsigned int, f);
    u = (u + 0x7FFFu + ((u >> 16) & 1u)) >> 16;   // round-to-nearest-even
    return (unsigned short)u;
}

// pack 2 f32 -> 2 bf16 (RNE) in one instruction
__device__ __forceinline__ unsigned int cvt_pk_bf16(float a, float b) {
    unsigned int r;
    asm("v_cvt_pk_bf16_f32 %0, %1, %2" : "=v"(r) : "v"(a), "v"(b));
    return r;
}

__device__ __forceinline__ float fast_tanh(float x) {
    // tanh(x) = 1 - 2/(1+2^(2x*log2e)); saturations via exp inf/0
    float e = __builtin_amdgcn_exp2f(x * 2.88539008177793f);
    return __builtin_fmaf(-2.0f, __builtin_amdgcn_rcpf(e + 1.0f), 1.0f);
}

// ---- prep: W (500x512 f32) -> bf16, padded to 512 rows, tiled [kc][v][32] ----
__global__ void prep_w(const float* __restrict__ W, unsigned short* __restrict__ Wt) {
    int idx = blockIdx.x * 256 + threadIdx.x;   // 0 .. 512*512-1
    int k = idx & 511;
    int v = idx >> 9;
    float val = (v < VV) ? W[v * DD + k] : 0.0f;
    Wt[(k >> 5) * (VP * BK) + v * BK + (k & 31)] = f2bf(val);
}

// One K-step. At entry: CUR holds A[kc] (barrier passed), BC holds B[kc]
// (loads in flight, counted-vmcnt at consume), e/d regs hold enc/dec[kc+1].
#define KBODY(kc, CUR, NXT, BC, BNX)                                          \
  {                                                                           \
    /* issue next step's B fragments (stay in flight across the barrier) */   \
    if ((kc) < KSTEPS - 1) {                                                  \
      _Pragma("unroll")                                                       \
      for (int f = 0; f < 8; ++f)                                             \
        BNX[f] = *(const s16x8*)(wptr + ((kc)+1) * (VP * BK) + f * (16*BK));  \
    }                                                                         \
    /* A fragments for this step */                                           \
    s16x8 aF[4];                                                              \
    _Pragma("unroll")                                                         \
    for (int m = 0; m < 4; ++m)                                               \
      aF[m] = *(const s16x8*)(&CUR[(m * 16 + lr) * LDA + lk * 8]);            \
    /* stage A[kc+1] from e/d regs, then load e/d for kc+2 */                 \
    if ((kc) < KSTEPS - 1) {                                                  \
      u32x4 wds;                                                              \
      wds[0] = cvt_pk_bf16(fast_tanh(e0[0]+d0[0]), fast_tanh(e0[1]+d0[1]));   \
      wds[1] = cvt_pk_bf16(fast_tanh(e0[2]+d0[2]), fast_tanh(e0[3]+d0[3]));   \
      wds[2] = cvt_pk_bf16(fast_tanh(e1[0]+d1[0]), fast_tanh(e1[1]+d1[1]));   \
      wds[3] = cvt_pk_bf16(fast_tanh(e1[2]+d1[2]), fast_tanh(e1[3]+d1[3]));   \
      *(u32x4*)(&NXT[srow * LDA + sk]) = wds;                                 \
      if ((kc) < KSTEPS - 2) {                                                \
        const float* e2 = ep + ((kc)+2) * BK;                                 \
        const float* d2 = dp + ((kc)+2) * BK;                                 \
        e0 = *(const f32x4*)(e2);  e1 = *(const f32x4*)(e2 + 4);              \
        d0 = *(const f32x4*)(d2);  d1 = *(const f32x4*)(d2 + 4);              \
      }                                                                       \
    }                                                                         \
    /* 32 MFMAs on BC (compiler emits counted vmcnt, not 0) */                \
    __builtin_amdgcn_s_setprio(1);                                            \
    _Pragma("unroll")                                                         \
    for (int m = 0; m < 4; ++m)                                               \
      _Pragma("unroll")                                                       \
      for (int f = 0; f < 8; ++f)                                             \
        acc[m][f] = __builtin_amdgcn_mfma_f32_16x16x32_bf16(aF[m], BC[f],     \
                                                            acc[m][f],0,0,0); \
    __builtin_amdgcn_s_setprio(0);                                            \
    /* raw barrier: drain LDS only, keep global loads in flight */            \
    if ((kc) < KSTEPS - 1) {                                                  \
      asm volatile("s_waitcnt lgkmcnt(0)" ::: "memory");                      \
      __builtin_amdgcn_s_barrier();                                           \
    }                                                                         \
  }

__global__ __launch_bounds__(THREADS, 2) void joiner_kernel(
    const float* __restrict__ enc, const float* __restrict__ dec,
    const unsigned short* __restrict__ Wt, const float* __restrict__ bias,
    float* __restrict__ out)
{
    // union: K-loop A dbuf (2 x 5120 B) / epilogue chunk 16x500 f32 (32000 B)
    __shared__ __align__(16) char smem[32000];
    unsigned short* lA0 = (unsigned short*)smem;
    unsigned short* lA1 = (unsigned short*)(smem + BM * LDA * 2);

    const int tid  = threadIdx.x;
    const int mb   = blockIdx.x;
    const int lane = tid & 63;
    const int wn   = tid >> 6;       // 0..3: 128-col quarter
    const int lr   = lane & 15;
    const int lk   = lane >> 4;

    // staging: each thread produces 8 activations of one row
    const int srow = tid >> 2;          // 0..63
    const int sk   = (tid & 3) << 3;    // 0,8,16,24

    int r   = mb * BM + srow;
    int n   = r / (TT * UU);
    int rem = r - n * (TT * UU);
    int t   = rem / UU;
    int u   = rem - t * UU;
    const float* ep = enc + (n * TT + t) * DD + sk;
    const float* dp = dec + (n * UU + u) * DD + sk;

    // per-thread B pointer into pre-tiled Wt: v = wn*128 + f*16 + lr, k = lk*8
    const unsigned short* wptr = Wt + (wn * 128 + lr) * BK + lk * 8;

    f32x4 e0, e1, d0, d1;
    s16x8 b0[8], b1[8];

    // ---- prologue: e/d[0], issue B[0], stage A[0], e/d[1], barrier ----
    e0 = *(const f32x4*)(ep);     e1 = *(const f32x4*)(ep + 4);
    d0 = *(const f32x4*)(dp);     d1 = *(const f32x4*)(dp + 4);
    #pragma unroll
    for (int f = 0; f < 8; ++f)
        b0[f] = *(const s16x8*)(wptr + f * (16 * BK));
    {
        u32x4 wds;
        wds[0] = cvt_pk_bf16(fast_tanh(e0[0]+d0[0]), fast_tanh(e0[1]+d0[1]));
        wds[1] = cvt_pk_bf16(fast_tanh(e0[2]+d0[2]), fast_tanh(e0[3]+d0[3]));
        wds[2] = cvt_pk_bf16(fast_tanh(e1[0]+d1[0]), fast_tanh(e1[1]+d1[1]));
        wds[3] = cvt_pk_bf16(fast_tanh(e1[2]+d1[2]), fast_tanh(e1[3]+d1[3]));
        *(u32x4*)(&lA0[srow * LDA + sk]) = wds;
    }
    e0 = *(const f32x4*)(ep + BK);     e1 = *(const f32x4*)(ep + BK + 4);
    d0 = *(const f32x4*)(dp + BK);     d1 = *(const f32x4*)(dp + BK + 4);
    asm volatile("s_waitcnt lgkmcnt(0)" ::: "memory");
    __builtin_amdgcn_s_barrier();

    f32x4 acc[4][8];
    #pragma unroll
    for (int m = 0; m < 4; ++m)
        #pragma unroll
        for (int f = 0; f < 8; ++f)
            acc[m][f] = (f32x4){0.f, 0.f, 0.f, 0.f};

    // ---- K-loop: 8 x 2 bodies; B reg-dbuf b0/b1, A LDS-dbuf lA0/lA1 ----
    #pragma unroll
    for (int kk = 0; kk < KSTEPS; kk += 2) {
        KBODY(kk,     lA0, lA1, b0, b1)
        KBODY(kk + 1, lA1, lA0, b1, b0)
    }

    // ---- epilogue: acc -> LDS 16-row chunks -> streaming f32x4 stores ----
    float bv[8];
    #pragma unroll
    for (int f = 0; f < 8; ++f) {
        int v = wn * 128 + f * 16 + lr;
        bv[f] = (v < VV) ? bias[v] : 0.0f;
    }

    float* lchunk = (float*)smem;                 // 16*500 f32 = 32000 B
    float* outbase = out + (long)mb * BM * VV;

    for (int m = 0; m < 4; ++m) {
        __syncthreads();   // waves converge / previous chunk fully streamed
        #pragma unroll
        for (int f = 0; f < 8; ++f) {
            int v = wn * 128 + f * 16 + lr;
            if (v < VV) {
                #pragma unroll
                for (int q = 0; q < 4; ++q)
                    lchunk[(lk * 4 + q) * VV + v] = acc[m][f][q] + bv[f];
            }
        }
        __syncthreads();
        // 16 rows x 500 f32 = 8000 contiguous floats = 2000 f32x4
        float* dst = outbase + m * 16 * VV;
        #pragma unroll
        for (int i = 0; i < 8; ++i) {
            int c = i * THREADS + tid;
            if (c < 2000)
                *(f32x4*)(dst + c * 4) = *(const f32x4*)(lchunk + c * 4);
        }
    }
}

extern "C" void kernel_launch(void* const* d_in, const int* in_sizes, int n_in,
                              void* d_out, int out_size, void* d_ws, size_t ws_size,
                              hipStream_t stream) {
    const float* enc = (const float*)d_in[0];
    const float* dec = (const float*)d_in[1];
    const float* W   = (const float*)d_in[2];
    const float* b   = (const float*)d_in[3];
    float* out = (float*)d_out;
    unsigned short* Wt = (unsigned short*)d_ws;   // 512*512*2 = 512 KB

    prep_w<<<dim3((VP * DD) / 256), dim3(256), 0, stream>>>(W, Wt);
    joiner_kernel<<<dim3(MBLOCKS), dim3(THREADS), 0, stream>>>(enc, dec, Wt, b, out);
}